// Round 1
// baseline (1961.291 us; speedup 1.0000x reference)
//
#include <hip/hip_runtime.h>
#include <math.h>

using f4 = __attribute__((ext_vector_type(4))) float;

#define THREADS 256
#define PX      64      // pixels per block
#define IT      128     // items per chunk
#define KC      64      // k-slice
#define DIMC    512
#define NITEM   2048
#define NCHUNK  (NITEM / IT)   // 16
#define NSLICE  (DIMC / KC)    // 8
#define TK      10

// LDS layout (float offsets). Phases are barrier-separated; regions overlay.
#define Q_OFF   0        // q slice  [KC][PX]          = 4096 floats
#define MP_OFF  4096     // mp slice [KC][IT] swizzled = 8192 floats
#define S_STRIDE 68      // S overlay [IT][68] at 0    = 8704 floats
#define MV_OFF  0        // merge vals [PX][4][TK]     = 2560
#define MI_OFF  2560     // merge idx  [PX][4][TK]     = 2560
#define MM_OFF  5120     // merge max  [PX][4]         = 256
#define MS_OFF  5376     // merge sum  [PX][4]         = 256
#define WB_OFF  8704     // weights [PX][TK]           = 640
#define IB_OFF  9344     // indices [PX][TK]           = 640
#define LDS_FLOATS 12288 // 49,152 B -> 3 blocks/CU by LDS

__global__ __launch_bounds__(THREADS, 2)
void memorize_kernel(const float* __restrict__ x0,
                     const float* __restrict__ x1,
                     const float* __restrict__ mp,
                     float* __restrict__ out)
{
    __shared__ float lds[LDS_FLOATS];

    const int t   = threadIdx.x;
    const int blk = blockIdx.x;          // 0..511
    const int img = blk >> 4;            // 0..31 (0..15 input1, 16..31 input2)
    const int n0  = (blk & 15) * PX;     // pixel base within image (HW=1024)
    const int b   = img & 15;

    const float* x  = (img < 16) ? x0 : x1;
    const float* xb = x + (size_t)b * (DIMC * 1024);
    float* ob = out + (img < 16 ? (size_t)0 : (size_t)16 * DIMC * 1024)
                    + (size_t)b * (DIMC * 1024);

    // GEMM thread mapping: 16 item-groups x 16 pixel-groups
    const int ti = t & 15;   // item group: items ti*4..+3 and 64+ti*4..+3
    const int pi = t >> 4;   // pixel group: pixels pi*4..+3

    // staging / scan mapping
    const int qp  = t & 63;  // pixel lane
    const int qc  = t >> 6;  // 0..3
    const int mk4 = t & 15;  // k-quad for mp staging
    const int mi0 = t >> 4;  // item base for mp staging

    // Precomputed swizzled mp read bases for j = k & 15 (compile-time indexed)
    int mpbase[16];
#pragma unroll
    for (int j = 0; j < 16; ++j)
        mpbase[j] = MP_OFF + j * 128 + ((ti ^ j) << 2);
    const int qbase = Q_OFF + (pi << 2);

    // per-thread online state: this thread scans 512 of 2048 items for pixel qp
    float tv[TK];
    int   tix[TK];
#pragma unroll
    for (int q = 0; q < TK; ++q) { tv[q] = -INFINITY; tix[q] = 0x7fffffff; }
    float rm = -INFINITY, rs = 0.0f;

#pragma unroll 1
    for (int chunk = 0; chunk < NCHUNK; ++chunk) {
        const int m0 = chunk * IT;
        float acc[8][4];
#pragma unroll
        for (int i = 0; i < 8; ++i)
#pragma unroll
            for (int p = 0; p < 4; ++p) acc[i][p] = 0.0f;

#pragma unroll 1
        for (int ks = 0; ks < NSLICE; ++ks) {
            __syncthreads();  // previous-phase LDS reads done before we overwrite
            // ---- stage q slice: [KC][PX], straight copy (x is [C][HW]) ----
            {
                const float* src = xb + (size_t)(ks * KC) * 1024 + n0 + qp;
#pragma unroll
                for (int i = 0; i < 16; ++i) {
                    int c = qc * 16 + i;
                    lds[Q_OFF + c * 64 + qp] = src[(size_t)c * 1024];
                }
            }
            // ---- stage mp slice: transpose to [KC][IT] with XOR granule swizzle ----
            {
#pragma unroll
                for (int pass = 0; pass < 8; ++pass) {
                    int item = mi0 + pass * 16;
                    const f4 v = *(const f4*)(mp + (size_t)(m0 + item) * DIMC
                                                 + ks * KC + mk4 * 4);
                    int half = (item >> 6) << 6;     // 0 or 64
                    int gh   = (item >> 2) & 15;
                    int r    = item & 3;
#pragma unroll
                    for (int j = 0; j < 4; ++j) {
                        int k = mk4 * 4 + j;
                        lds[MP_OFF + k * 128 + half + (((gh ^ (k & 15))) << 2) + r] = v[j];
                    }
                }
            }
            __syncthreads();
            // ---- GEMM over this k-slice: 3x ds_read_b128 per 32 FMA ----
            for (int ko = 0; ko < 4; ++ko) {
                const int koff  = ko * 2048;
                const int qkoff = ko * 1024;
#pragma unroll
                for (int j = 0; j < 16; ++j) {
                    f4 a0 = *(const f4*)(lds + mpbase[j] + koff);
                    f4 a1 = *(const f4*)(lds + mpbase[j] + koff + 64);
                    f4 qv = *(const f4*)(lds + qbase + qkoff + j * 64);
#pragma unroll
                    for (int p = 0; p < 4; ++p) {
#pragma unroll
                        for (int i = 0; i < 4; ++i) {
                            acc[i][p]     = fmaf(a0[i], qv[p], acc[i][p]);
                            acc[4 + i][p] = fmaf(a1[i], qv[p], acc[4 + i][p]);
                        }
                    }
                }
            }
        }

        // ---- stage chunk scores S [IT][68] (overlay), conflict-free b128 ----
        __syncthreads();
#pragma unroll
        for (int i = 0; i < 8; ++i) {
            int il = (i < 4) ? (ti * 4 + i) : (64 + ti * 4 + (i - 4));
            f4 v; v[0] = acc[i][0]; v[1] = acc[i][1]; v[2] = acc[i][2]; v[3] = acc[i][3];
            *(f4*)(lds + il * S_STRIDE + (pi << 2)) = v;
        }
        __syncthreads();

        // ---- scan: 4 threads per pixel, 32 items each: online softmax + top-10 ----
        {
            const int g = qc;
#pragma unroll 4
            for (int jj = 0; jj < 32; ++jj) {
                int   il = g * 32 + jj;
                float v  = lds[il * S_STRIDE + qp];
                int   id = m0 + il;
                float mn = fmaxf(rm, v);
                rs = rs * __expf(rm - mn) + __expf(v - mn);
                rm = mn;
                // static-unrolled sorted insert (desc; strict > keeps lower index on ties)
                float cv = v; int ci = id;
#pragma unroll
                for (int q = 0; q < TK; ++q) {
                    bool  gt = cv > tv[q];
                    float nv = gt ? tv[q]  : cv;
                    int   ni = gt ? tix[q] : ci;
                    tv[q]  = gt ? cv : tv[q];
                    tix[q] = gt ? ci : tix[q];
                    cv = nv; ci = ni;
                }
            }
        }
    }

    // ---- dump per-thread state for merge ----
    __syncthreads();
    {
        const int g = qc, p = qp;
#pragma unroll
        for (int q = 0; q < TK; ++q) {
            lds[MV_OFF + (p * 4 + g) * TK + q] = tv[q];
            lds[MI_OFF + (p * 4 + g) * TK + q] = __int_as_float(tix[q]);
        }
        lds[MM_OFF + p * 4 + g] = rm;
        lds[MS_OFF + p * 4 + g] = rs;
    }
    __syncthreads();

    // ---- merge 4 partial lists per pixel; compute p, then second softmax ----
    if (t < 64) {
        const int p = t;
        float gm[4], gs[4];
#pragma unroll
        for (int g = 0; g < 4; ++g) {
            gm[g] = lds[MM_OFF + p * 4 + g];
            gs[g] = lds[MS_OFF + p * 4 + g];
        }
        float mstar = fmaxf(fmaxf(gm[0], gm[1]), fmaxf(gm[2], gm[3]));
        float Z = gs[0] * __expf(gm[0] - mstar) + gs[1] * __expf(gm[1] - mstar)
                + gs[2] * __expf(gm[2] - mstar) + gs[3] * __expf(gm[3] - mstar);

        int h0 = 0, h1 = 0, h2 = 0, h3 = 0;
        float ov[TK]; int oi[TK];
#pragma unroll
        for (int o = 0; o < TK; ++o) {
            float bv = -INFINITY; int bi = 0x7fffffff; int bg = 0;
#define SEL(G, HG)                                                              \
            {                                                                   \
                float v  = lds[MV_OFF + (p * 4 + G) * TK + (HG)];               \
                int   id = __float_as_int(lds[MI_OFF + (p * 4 + G) * TK + (HG)]); \
                if (v > bv || (v == bv && id < bi)) { bv = v; bi = id; bg = G; } \
            }
            SEL(0, h0) SEL(1, h1) SEL(2, h2) SEL(3, h3)
#undef SEL
            ov[o] = bv; oi[o] = bi;
            h0 += (bg == 0); h1 += (bg == 1); h2 += (bg == 2); h3 += (bg == 3);
        }
        // first-softmax probabilities of the top-10 (exact reference semantics)
        float pv[TK];
#pragma unroll
        for (int o = 0; o < TK; ++o) pv[o] = __expf(ov[o] - mstar) / Z;
        // second softmax over the 10 probabilities
        float pmax = pv[0];
        float w[TK]; float W = 0.0f;
#pragma unroll
        for (int o = 0; o < TK; ++o) { w[o] = __expf(pv[o] - pmax); W += w[o]; }
#pragma unroll
        for (int o = 0; o < TK; ++o) {
            lds[WB_OFF + p * TK + o] = w[o] / W;
            lds[IB_OFF + p * TK + o] = __int_as_float(oi[o]);
        }
    }
    __syncthreads();

    // ---- epilogue: out[:, c, n] = sum_k w_k * mempool[idx_k][c] ----
    {
        const int p = qp, cg = qc;
        float wr[TK]; const float* rows[TK];
#pragma unroll
        for (int o = 0; o < TK; ++o) {
            wr[o]   = lds[WB_OFF + p * TK + o];
            rows[o] = mp + (size_t)__float_as_int(lds[IB_OFF + p * TK + o]) * DIMC;
        }
        float* obase = ob + n0 + p;
#pragma unroll 4
        for (int c4 = 0; c4 < 32; ++c4) {
            int c = cg * 128 + c4 * 4;
            f4 a = {0.0f, 0.0f, 0.0f, 0.0f};
#pragma unroll
            for (int o = 0; o < TK; ++o) {
                f4 r = *(const f4*)(rows[o] + c);
#pragma unroll
                for (int z = 0; z < 4; ++z) a[z] = fmaf(wr[o], r[z], a[z]);
            }
#pragma unroll
            for (int z = 0; z < 4; ++z) obase[(size_t)(c + z) * 1024] = a[z];
        }
    }
}

extern "C" void kernel_launch(void* const* d_in, const int* in_sizes, int n_in,
                              void* d_out, int out_size, void* d_ws, size_t ws_size,
                              hipStream_t stream) {
    const float* x0  = (const float*)d_in[0];
    const float* x1  = (const float*)d_in[1];
    const float* mpl = (const float*)d_in[2];
    float* out = (float*)d_out;
    memorize_kernel<<<dim3(512), dim3(THREADS), 0, stream>>>(x0, x1, mpl, out);
}

// Round 3
// 903.319 us; speedup vs baseline: 2.1712x; 2.1712x over previous
//
#include <hip/hip_runtime.h>
#include <math.h>

typedef __attribute__((ext_vector_type(4))) float f4;
typedef __attribute__((ext_vector_type(8))) short bf16x8;
typedef __attribute__((ext_vector_type(4))) unsigned short u16x4;
typedef unsigned int u32;
typedef unsigned short u16;

#define DIMC  512
#define NITEM 2048
#define TK    10
#define WSP   (NITEM * DIMC)        // ws plane stride (u16 elems) = 1048576

// ---------------- main kernel geometry ----------------
#define TPB    512                  // 8 waves
#define PXB    64                   // pixels per block
#define RIT    512                  // items per round
#define NRND   4
#define NSLICE 16                   // K-slices of 32 (K=512)

// ---------------- LDS layout (bytes) ----------------
//   staging: mp planes [3][512 items][64B k-slice] at 0..98303
//   S overlay [512][66] f32 at 0..135167 (after k-loop, staging dead)
//   q planes [3][64 px][64B] at 135168..147455 (restaged EVERY slice)
//   merge arrays overlay S low region at the very end
#define MP_B   0
#define S_B    0
#define SSTR   66
#define Q_B    135168
#define LDS_BYTES 147456
// merge overlay (float indices from base 0)
#define MV_F 0        // [64][8][10] vals
#define MI_F 5120     // [64][8][10] idx
#define MM_F 10240    // [64][8] max
#define MS_F 10752    // [64][8] sum
#define WB_F 11264    // [64][10] weights
#define IB_F 11904    // [64][10] indices

__device__ __forceinline__ u32 bf16_rne(float f) {
    u32 u = __float_as_uint(f);
    return (u + 0x7fffu + ((u >> 16) & 1u)) >> 16;
}

// Convert mempool fp32 -> 3 bf16 planes in ws, k stored in MFMA fragment
// permutation: within each 32-k slice, position = h*8 + pair*4 + j for
// k_local = pair*16 + h*4 + j (identical perm for A and B -> correctness-
// invariant to the true HW k-grouping).
__global__ __launch_bounds__(256)
void preconv_kernel(const float* __restrict__ mp, u16* __restrict__ ws)
{
    int idx = (blockIdx.x * 256 + threadIdx.x) * 4;   // 1024 blocks -> exact
    int i  = idx >> 9;
    int k0 = idx & 511;                               // 4-aligned
    f4 v = *(const f4*)(mp + (size_t)i * 512 + k0);
    int s  = k0 >> 5, kl = k0 & 31;
    int pos = s * 32 + ((kl >> 2) & 3) * 8 + (kl >> 4) * 4;  // + j (j=0..3)
    u16x4 p0, p1, p2;
#pragma unroll
    for (int e = 0; e < 4; ++e) {
        float f  = v[e];
        u32 b0   = bf16_rne(f);  float f0 = __uint_as_float(b0 << 16);
        float r1 = f - f0;
        u32 b1   = bf16_rne(r1); float f1 = __uint_as_float(b1 << 16);
        float r2 = r1 - f1;
        u32 b2   = bf16_rne(r2);
        p0[e] = (u16)b0; p1[e] = (u16)b1; p2[e] = (u16)b2;
    }
    size_t base = (size_t)i * 512 + pos;
    *(u16x4*)(ws + 0 * WSP + base) = p0;
    *(u16x4*)(ws + 1 * WSP + base) = p1;
    *(u16x4*)(ws + 2 * WSP + base) = p2;
}

__global__ __launch_bounds__(TPB, 2)
void memorize_mfma(const float* __restrict__ x0, const float* __restrict__ x1,
                   const float* __restrict__ mp, const u16* __restrict__ ws,
                   float* __restrict__ out)
{
    extern __shared__ char ldsb[];
    float* ldsf = (float*)ldsb;

    const int t    = threadIdx.x;
    const int lane = t & 63;
    const int w    = t >> 6;            // wave 0..7
    const int blk  = blockIdx.x;        // 0..511
    const int img  = blk >> 4;          // 0..31
    const int n0   = (blk & 15) * PXB;  // pixel base (HW = 1024)
    const int b    = img & 15;

    const float* x  = (img < 16) ? x0 : x1;
    const float* xb = x + (size_t)b * (DIMC * 1024);
    float* ob = out + (img < 16 ? (size_t)0 : (size_t)16 * DIMC * 1024)
                    + (size_t)b * (DIMC * 1024);

    const int l15 = lane & 15;
    const int lh  = lane >> 4;          // fragment h-group 0..3

    // scan mapping: 8 groups of 64 items per round per pixel
    const int qp = t & 63;
    const int g  = t >> 6;

    float tv[TK]; int tix[TK];
#pragma unroll
    for (int q = 0; q < TK; ++q) { tv[q] = -INFINITY; tix[q] = 0x7fffffff; }
    float rm = -INFINITY, rs = 0.0f;

    // q staging mapping: thread -> (k-local scl, 4 px)
    const int scl  = t & 31;
    const int spx  = (t >> 5) << 2;     // 0..60
    const int spos = (((scl >> 2) & 3) << 3) + ((scl >> 4) << 2) + (scl & 3);

    // fragment LDS base addresses
    const char* qb = ldsb + Q_B + (l15 << 6) + (lh << 4);
    const char* ab = ldsb + MP_B + (size_t)((w << 6) + l15) * 64 + (lh << 4);

#pragma unroll 1
    for (int r = 0; r < NRND; ++r) {
        f4 acc[4][4];
#pragma unroll
        for (int mt = 0; mt < 4; ++mt)
#pragma unroll
            for (int nt = 0; nt < 4; ++nt) acc[mt][nt] = (f4){0.f, 0.f, 0.f, 0.f};

#pragma unroll 1
        for (int s = 0; s < NSLICE; ++s) {
            __syncthreads();   // prev slice frag reads / prev round scan done

            // ---- issue mp staging first: 12 x global_load_lds(16B) ----
            {
                const int itq = lane >> 2;   // 0..15
                const int slo = lane & 3;    // 16B slot
#pragma unroll
                for (int p = 0; p < 3; ++p) {
#pragma unroll
                    for (int qg = 0; qg < 4; ++qg) {
                        int I = (w << 6) + (qg << 4);          // item-local base
                        const u16* src = ws + (size_t)p * WSP
                                       + (size_t)(r * RIT + I + itq) * 512
                                       + (s << 5) + (slo << 3);
                        char* dst = ldsb + MP_B + p * 32768 + I * 64;
                        __builtin_amdgcn_global_load_lds(
                            (const __attribute__((address_space(1))) u32*)src,
                            (__attribute__((address_space(3))) u32*)dst, 16, 0, 0);
                    }
                }
            }

            // ---- stage q slice (EVERY round: Q holds only one slice) ----
            {
                const float* src = xb + (size_t)((s << 5) + scl) * 1024 + n0 + spx;
                f4 v = *(const f4*)src;
#pragma unroll
                for (int e = 0; e < 4; ++e) {
                    float f  = v[e];
                    u32 b0   = bf16_rne(f);  float f0 = __uint_as_float(b0 << 16);
                    float r1 = f - f0;
                    u32 b1   = bf16_rne(r1); float f1 = __uint_as_float(b1 << 16);
                    float r2 = r1 - f1;
                    u32 b2   = bf16_rne(r2);
                    int ro = Q_B + ((spx + e) << 6) + (spos << 1);
                    *(u16*)(ldsb + ro)        = (u16)b0;
                    *(u16*)(ldsb + ro + 4096) = (u16)b1;
                    *(u16*)(ldsb + ro + 8192) = (u16)b2;
                }
            }
            __syncthreads();

            // ---- MFMA: 16 tiles x 6 split-products ----
            bf16x8 bq[4][3];
#pragma unroll
            for (int nt = 0; nt < 4; ++nt)
#pragma unroll
                for (int p = 0; p < 3; ++p)
                    bq[nt][p] = *(const bf16x8*)(qb + p * 4096 + nt * 1024);

#pragma unroll
            for (int mt = 0; mt < 4; ++mt) {
                bf16x8 a0 = *(const bf16x8*)(ab +     0 + mt * 1024);
                bf16x8 a1 = *(const bf16x8*)(ab + 32768 + mt * 1024);
                bf16x8 a2 = *(const bf16x8*)(ab + 65536 + mt * 1024);
#pragma unroll
                for (int nt = 0; nt < 4; ++nt) {
                    f4 c = acc[mt][nt];
                    c = __builtin_amdgcn_mfma_f32_16x16x32_bf16(a0, bq[nt][0], c, 0, 0, 0);
                    c = __builtin_amdgcn_mfma_f32_16x16x32_bf16(a0, bq[nt][1], c, 0, 0, 0);
                    c = __builtin_amdgcn_mfma_f32_16x16x32_bf16(a1, bq[nt][0], c, 0, 0, 0);
                    c = __builtin_amdgcn_mfma_f32_16x16x32_bf16(a0, bq[nt][2], c, 0, 0, 0);
                    c = __builtin_amdgcn_mfma_f32_16x16x32_bf16(a1, bq[nt][1], c, 0, 0, 0);
                    c = __builtin_amdgcn_mfma_f32_16x16x32_bf16(a2, bq[nt][0], c, 0, 0, 0);
                    acc[mt][nt] = c;
                }
            }
        }

        // ---- drain accs to S overlay: row=item-local, col=px ----
        __syncthreads();
#pragma unroll
        for (int mt = 0; mt < 4; ++mt) {
#pragma unroll
            for (int nt = 0; nt < 4; ++nt) {
                int row = (w << 6) + (mt << 4) + (lh << 2);   // + reg
                int col = (nt << 4) + l15;
                float* sp = ldsf + row * SSTR + col;
                sp[0 * SSTR] = acc[mt][nt][0];
                sp[1 * SSTR] = acc[mt][nt][1];
                sp[2 * SSTR] = acc[mt][nt][2];
                sp[3 * SSTR] = acc[mt][nt][3];
            }
        }
        __syncthreads();

        // ---- scan sweep 1: max + guarded top-10 insert (64 items/thread) ----
        float mloc = rm;
#pragma unroll 4
        for (int jj = 0; jj < 64; ++jj) {
            int   il = (g << 6) + jj;
            float v  = ldsf[il * SSTR + qp];
            mloc = fmaxf(mloc, v);
            if (v > tv[TK - 1]) {
                int   id = r * RIT + il;
                float cv = v; int ci = id;
#pragma unroll
                for (int q = 0; q < TK; ++q) {
                    bool  gt = cv > tv[q];
                    float nv = gt ? tv[q]  : cv;
                    int   ni = gt ? tix[q] : ci;
                    tv[q]  = gt ? cv : tv[q];
                    tix[q] = gt ? ci : tix[q];
                    cv = nv; ci = ni;
                }
            }
        }
        // rescale old sum to the new max (round 0: rs==0, exp(-inf)=0 -> ok)
        rs *= __expf(rm - mloc);
        rm = mloc;
        // ---- scan sweep 2: exp-sum at fixed max ----
#pragma unroll 4
        for (int jj = 0; jj < 64; ++jj) {
            int   il = (g << 6) + jj;
            float v  = ldsf[il * SSTR + qp];
            rs += __expf(v - rm);
        }
    }

    // ---- dump per-thread partials for merge ----
    __syncthreads();
    {
#pragma unroll
        for (int q = 0; q < TK; ++q) {
            ldsf[MV_F + (qp * 8 + g) * TK + q] = tv[q];
            ldsf[MI_F + (qp * 8 + g) * TK + q] = __int_as_float(tix[q]);
        }
        ldsf[MM_F + qp * 8 + g] = rm;
        ldsf[MS_F + qp * 8 + g] = rs;
    }
    __syncthreads();

    // ---- merge 8 partial lists per pixel; double softmax ----
    if (t < 64) {
        const int p = t;
        float gm[8], gs[8];
#pragma unroll
        for (int G = 0; G < 8; ++G) {
            gm[G] = ldsf[MM_F + p * 8 + G];
            gs[G] = ldsf[MS_F + p * 8 + G];
        }
        float mstar = gm[0];
#pragma unroll
        for (int G = 1; G < 8; ++G) mstar = fmaxf(mstar, gm[G]);
        float Z = 0.0f;
#pragma unroll
        for (int G = 0; G < 8; ++G) Z += gs[G] * __expf(gm[G] - mstar);

        int h0=0,h1=0,h2=0,h3=0,h4=0,h5=0,h6=0,h7=0;
        float ov[TK]; int oi[TK];
#pragma unroll
        for (int o = 0; o < TK; ++o) {
            float bv = -INFINITY; int bi = 0x7fffffff; int bg = 0;
#define SEL(G, HG)                                                               \
            {                                                                    \
                float v  = ldsf[MV_F + (p * 8 + G) * TK + (HG)];                 \
                int   id = __float_as_int(ldsf[MI_F + (p * 8 + G) * TK + (HG)]); \
                if (v > bv || (v == bv && id < bi)) { bv = v; bi = id; bg = G; } \
            }
            SEL(0, h0) SEL(1, h1) SEL(2, h2) SEL(3, h3)
            SEL(4, h4) SEL(5, h5) SEL(6, h6) SEL(7, h7)
#undef SEL
            ov[o] = bv; oi[o] = bi;
            h0 += (bg == 0); h1 += (bg == 1); h2 += (bg == 2); h3 += (bg == 3);
            h4 += (bg == 4); h5 += (bg == 5); h6 += (bg == 6); h7 += (bg == 7);
        }
        float pv[TK];
#pragma unroll
        for (int o = 0; o < TK; ++o) pv[o] = __expf(ov[o] - mstar) / Z;
        float pmax = pv[0];
        float wgt[TK]; float W = 0.0f;
#pragma unroll
        for (int o = 0; o < TK; ++o) { wgt[o] = __expf(pv[o] - pmax); W += wgt[o]; }
#pragma unroll
        for (int o = 0; o < TK; ++o) {
            ldsf[WB_F + p * TK + o] = wgt[o] / W;
            ldsf[IB_F + p * TK + o] = __int_as_float(oi[o]);
        }
    }
    __syncthreads();

    // ---- epilogue: out[:, c, n] = sum_k w_k * mempool[idx_k][c] ----
    {
        const int ep = t & 63, cg = t >> 6;   // 8 c-groups x 64 channels
        float wr[TK]; const float* rows[TK];
#pragma unroll
        for (int o = 0; o < TK; ++o) {
            wr[o]   = ldsf[WB_F + ep * TK + o];
            rows[o] = mp + (size_t)__float_as_int(ldsf[IB_F + ep * TK + o]) * DIMC;
        }
        float* obase = ob + n0 + ep;
#pragma unroll 4
        for (int cc = 0; cc < 16; ++cc) {
            int c = cg * 64 + cc * 4;
            f4 a = {0.0f, 0.0f, 0.0f, 0.0f};
#pragma unroll
            for (int o = 0; o < TK; ++o) {
                f4 rv = *(const f4*)(rows[o] + c);
#pragma unroll
                for (int z = 0; z < 4; ++z) a[z] = fmaf(wr[o], rv[z], a[z]);
            }
#pragma unroll
            for (int z = 0; z < 4; ++z) obase[(size_t)(c + z) * 1024] = a[z];
        }
    }
}

extern "C" void kernel_launch(void* const* d_in, const int* in_sizes, int n_in,
                              void* d_out, int out_size, void* d_ws, size_t ws_size,
                              hipStream_t stream) {
    const float* x0  = (const float*)d_in[0];
    const float* x1  = (const float*)d_in[1];
    const float* mpl = (const float*)d_in[2];
    float* out = (float*)d_out;
    u16* ws = (u16*)d_ws;

    preconv_kernel<<<dim3(1024), dim3(256), 0, stream>>>(mpl, ws);
    memorize_mfma<<<dim3(512), dim3(TPB), LDS_BYTES, stream>>>(x0, x1, mpl, ws, out);
}

// Round 4
// 642.511 us; speedup vs baseline: 3.0525x; 1.4059x over previous
//
#include <hip/hip_runtime.h>
#include <math.h>

typedef __attribute__((ext_vector_type(4))) float f4;
typedef __attribute__((ext_vector_type(8))) short bf16x8;
typedef __attribute__((ext_vector_type(4))) unsigned short u16x4;
typedef unsigned int u32;
typedef unsigned short u16;

#define DIMC  512
#define NITEM 2048
#define TK    10
#define WSP   (NITEM * DIMC)        // ws plane stride (u16 elems)

// ---------------- main kernel geometry ----------------
#define TPB    512                  // 8 waves
#define PXB    64                   // pixels per block
#define RIT    256                  // items per round
#define NRND   8
#define NSLICE 16                   // K-slices of 32 (K=512)

// ---------------- LDS layout (bytes) ----------------
//   staging: mp planes [3][256 items][64B k-slice] at 0..49151
//   S overlay [256][66] f32 at 0..67583 (staging dead after k-loop)
//   q planes [3][64 px][64B] at 67584..79871 (restaged every slice)
//   merge arrays overlay S low region after last scan
#define MP_B   0
#define MP_PL  16384     // per-plane bytes (256*64)
#define SSTR   66
#define Q_B    67584
#define Q_PL   4096
#define LDS_BYTES 79872  // 78 KB -> 2 blocks/CU
// merge overlay (float indices from base 0)
#define MV_F 0        // [64][8][10] vals
#define MI_F 5120     // [64][8][10] idx
#define MM_F 10240    // [64][8] max
#define MS_F 10752    // [64][8] sum
#define WB_F 11264    // [64][10] weights
#define IB_F 11904    // [64][10] indices

// bank-spread swizzle key for 16-row fragment tiles (2-way residual = free)
#define KSWZ(i) (((i) ^ ((i) >> 2)) & 3)

__device__ __forceinline__ u32 bf16_rne(float f) {
    u32 u = __float_as_uint(f);
    return (u + 0x7fffu + ((u >> 16) & 1u)) >> 16;
}

// Convert mempool fp32 -> 3 bf16 planes in ws, k stored in MFMA fragment
// permutation: within each 32-k slice, position = pair*8 + h*4 + j for
// k_local = pair*16 + h*4 + j (identical perm for A and B -> correctness-
// invariant to the true HW k-grouping).
__global__ __launch_bounds__(256)
void preconv_kernel(const float* __restrict__ mp, u16* __restrict__ ws)
{
    int idx = (blockIdx.x * 256 + threadIdx.x) * 4;   // 1024 blocks -> exact
    int i  = idx >> 9;
    int k0 = idx & 511;
    f4 v = *(const f4*)(mp + (size_t)i * 512 + k0);
    int s  = k0 >> 5, kl = k0 & 31;
    int pos = s * 32 + ((kl >> 2) & 3) * 8 + (kl >> 4) * 4;  // + j (j=0..3)
    u16x4 p0, p1, p2;
#pragma unroll
    for (int e = 0; e < 4; ++e) {
        float f  = v[e];
        u32 b0   = bf16_rne(f);  float f0 = __uint_as_float(b0 << 16);
        float r1 = f - f0;
        u32 b1   = bf16_rne(r1); float f1 = __uint_as_float(b1 << 16);
        float r2 = r1 - f1;
        u32 b2   = bf16_rne(r2);
        p0[e] = (u16)b0; p1[e] = (u16)b1; p2[e] = (u16)b2;
    }
    size_t base = (size_t)i * 512 + pos;
    *(u16x4*)(ws + 0 * WSP + base) = p0;
    *(u16x4*)(ws + 1 * WSP + base) = p1;
    *(u16x4*)(ws + 2 * WSP + base) = p2;
}

__global__ __launch_bounds__(TPB, 4)
void memorize_mfma(const float* __restrict__ x0, const float* __restrict__ x1,
                   const float* __restrict__ mp, const u16* __restrict__ ws,
                   float* __restrict__ out)
{
    extern __shared__ char ldsb[];
    float* ldsf = (float*)ldsb;

    const int t    = threadIdx.x;
    const int lane = t & 63;
    const int w    = t >> 6;            // wave 0..7
    const int blk  = blockIdx.x;        // 0..511
    const int img  = blk >> 4;          // 0..31
    const int n0   = (blk & 15) * PXB;  // pixel base (HW = 1024)
    const int b    = img & 15;

    const float* x  = (img < 16) ? x0 : x1;
    const float* xb = x + (size_t)b * (DIMC * 1024);
    float* ob = out + (img < 16 ? (size_t)0 : (size_t)16 * DIMC * 1024)
                    + (size_t)b * (DIMC * 1024);

    const int l15 = lane & 15;
    const int lh  = lane >> 4;          // fragment h-group 0..3
    const int ksw = lh ^ KSWZ(l15);     // swizzled 16B slot for frag reads

    // scan mapping: 8 groups of 32 items per round per pixel
    const int qp = t & 63;
    const int g  = t >> 6;

    float tv[TK]; int tix[TK];
#pragma unroll
    for (int q = 0; q < TK; ++q) { tv[q] = -INFINITY; tix[q] = 0x7fffffff; }
    float rm = -INFINITY, rs = 0.0f;

    // q staging mapping: thread -> (k-local scl, 4 px)
    const int scl  = t & 31;
    const int spx  = (t >> 5) << 2;     // 0..60
    const int spos = (((scl >> 2) & 3) << 3) + ((scl >> 4) << 2) + (scl & 3);
    const int sslot = spos >> 3;        // true 16B k-slot of this write
    const int soff  = (spos & 7) << 1;  // byte offset within slot

    // fragment LDS base addresses (swizzled)
    const char* qb = ldsb + Q_B + (l15 << 6) + (ksw << 4);
    const char* ab = ldsb + MP_B + (size_t)((w << 5) + l15) * 64 + (ksw << 4);

    // mp staging: per-lane source k-slot pre-swizzle (LDS dest stays linear)
    const int itq = lane >> 2;                 // item-local within 16-group
    const int slo = lane & 3;                  // LDS 16B slot this lane fills
    const int ksrc = slo ^ KSWZ(itq);          // true k-slot to fetch

#pragma unroll 1
    for (int r = 0; r < NRND; ++r) {
        f4 acc[2][4];
#pragma unroll
        for (int mt = 0; mt < 2; ++mt)
#pragma unroll
            for (int nt = 0; nt < 4; ++nt) acc[mt][nt] = (f4){0.f, 0.f, 0.f, 0.f};

#pragma unroll 1
        for (int s = 0; s < NSLICE; ++s) {
            __syncthreads();   // prev slice frag reads / prev round scan done

            // ---- issue mp staging first: 6 x global_load_lds(16B) ----
            {
#pragma unroll
                for (int p = 0; p < 3; ++p) {
#pragma unroll
                    for (int qg = 0; qg < 2; ++qg) {
                        int I = (w << 5) + (qg << 4);          // item-local base
                        const u16* src = ws + (size_t)p * WSP
                                       + (size_t)(r * RIT + I + itq) * 512
                                       + (s << 5) + (ksrc << 3);
                        char* dst = ldsb + MP_B + p * MP_PL + I * 64;
                        __builtin_amdgcn_global_load_lds(
                            (const __attribute__((address_space(1))) u32*)src,
                            (__attribute__((address_space(3))) u32*)dst, 16, 0, 0);
                    }
                }
            }

            // ---- stage q slice (every slice; swizzled ds_write) ----
            {
                const float* src = xb + (size_t)((s << 5) + scl) * 1024 + n0 + spx;
                f4 v = *(const f4*)src;
#pragma unroll
                for (int e = 0; e < 4; ++e) {
                    int px = spx + e;
                    float f  = v[e];
                    u32 b0   = bf16_rne(f);  float f0 = __uint_as_float(b0 << 16);
                    float r1 = f - f0;
                    u32 b1   = bf16_rne(r1); float f1 = __uint_as_float(b1 << 16);
                    float r2 = r1 - f1;
                    u32 b2   = bf16_rne(r2);
                    int ro = Q_B + (px << 6) + (((sslot ^ KSWZ(px)) << 4) | soff);
                    *(u16*)(ldsb + ro)            = (u16)b0;
                    *(u16*)(ldsb + ro + Q_PL)     = (u16)b1;
                    *(u16*)(ldsb + ro + 2 * Q_PL) = (u16)b2;
                }
            }
            __syncthreads();

            // ---- MFMA: 8 tiles x 6 split-products ----
            bf16x8 bq[4][3];
#pragma unroll
            for (int nt = 0; nt < 4; ++nt)
#pragma unroll
                for (int p = 0; p < 3; ++p)
                    bq[nt][p] = *(const bf16x8*)(qb + p * Q_PL + nt * 1024);

#pragma unroll
            for (int mt = 0; mt < 2; ++mt) {
                bf16x8 a0 = *(const bf16x8*)(ab + 0 * MP_PL + mt * 1024);
                bf16x8 a1 = *(const bf16x8*)(ab + 1 * MP_PL + mt * 1024);
                bf16x8 a2 = *(const bf16x8*)(ab + 2 * MP_PL + mt * 1024);
#pragma unroll
                for (int nt = 0; nt < 4; ++nt) {
                    f4 c = acc[mt][nt];
                    c = __builtin_amdgcn_mfma_f32_16x16x32_bf16(a0, bq[nt][0], c, 0, 0, 0);
                    c = __builtin_amdgcn_mfma_f32_16x16x32_bf16(a0, bq[nt][1], c, 0, 0, 0);
                    c = __builtin_amdgcn_mfma_f32_16x16x32_bf16(a1, bq[nt][0], c, 0, 0, 0);
                    c = __builtin_amdgcn_mfma_f32_16x16x32_bf16(a0, bq[nt][2], c, 0, 0, 0);
                    c = __builtin_amdgcn_mfma_f32_16x16x32_bf16(a1, bq[nt][1], c, 0, 0, 0);
                    c = __builtin_amdgcn_mfma_f32_16x16x32_bf16(a2, bq[nt][0], c, 0, 0, 0);
                    acc[mt][nt] = c;
                }
            }
        }

        // ---- drain accs to S overlay: row=item-local, col=px ----
        __syncthreads();
#pragma unroll
        for (int mt = 0; mt < 2; ++mt) {
#pragma unroll
            for (int nt = 0; nt < 4; ++nt) {
                int row = (w << 5) + (mt << 4) + (lh << 2);   // + reg
                int col = (nt << 4) + l15;
                float* sp = ldsf + row * SSTR + col;
                sp[0 * SSTR] = acc[mt][nt][0];
                sp[1 * SSTR] = acc[mt][nt][1];
                sp[2 * SSTR] = acc[mt][nt][2];
                sp[3 * SSTR] = acc[mt][nt][3];
            }
        }
        __syncthreads();

        // ---- scan sweep 1: max + guarded top-10 insert (32 items/thread) ----
        float mloc = rm;
#pragma unroll 4
        for (int jj = 0; jj < 32; ++jj) {
            int   il = (g << 5) + jj;
            float v  = ldsf[il * SSTR + qp];
            mloc = fmaxf(mloc, v);
            if (v > tv[TK - 1]) {
                int   id = r * RIT + il;
                float cv = v; int ci = id;
#pragma unroll
                for (int q = 0; q < TK; ++q) {
                    bool  gt = cv > tv[q];
                    float nv = gt ? tv[q]  : cv;
                    int   ni = gt ? tix[q] : ci;
                    tv[q]  = gt ? cv : tv[q];
                    tix[q] = gt ? ci : tix[q];
                    cv = nv; ci = ni;
                }
            }
        }
        rs *= __expf(rm - mloc);   // round 0: rs==0 -> ok
        rm = mloc;
        // ---- scan sweep 2: exp-sum at fixed max ----
#pragma unroll 4
        for (int jj = 0; jj < 32; ++jj) {
            int   il = (g << 5) + jj;
            float v  = ldsf[il * SSTR + qp];
            rs += __expf(v - rm);
        }
    }

    // ---- dump per-thread partials for merge ----
    __syncthreads();
    {
#pragma unroll
        for (int q = 0; q < TK; ++q) {
            ldsf[MV_F + (qp * 8 + g) * TK + q] = tv[q];
            ldsf[MI_F + (qp * 8 + g) * TK + q] = __int_as_float(tix[q]);
        }
        ldsf[MM_F + qp * 8 + g] = rm;
        ldsf[MS_F + qp * 8 + g] = rs;
    }
    __syncthreads();

    // ---- merge 8 partial lists per pixel; double softmax ----
    if (t < 64) {
        const int p = t;
        float gm[8], gs[8];
#pragma unroll
        for (int G = 0; G < 8; ++G) {
            gm[G] = ldsf[MM_F + p * 8 + G];
            gs[G] = ldsf[MS_F + p * 8 + G];
        }
        float mstar = gm[0];
#pragma unroll
        for (int G = 1; G < 8; ++G) mstar = fmaxf(mstar, gm[G]);
        float Z = 0.0f;
#pragma unroll
        for (int G = 0; G < 8; ++G) Z += gs[G] * __expf(gm[G] - mstar);

        int h0=0,h1=0,h2=0,h3=0,h4=0,h5=0,h6=0,h7=0;
        float ov[TK]; int oi[TK];
#pragma unroll
        for (int o = 0; o < TK; ++o) {
            float bv = -INFINITY; int bi = 0x7fffffff; int bg = 0;
#define SEL(G, HG)                                                               \
            {                                                                    \
                float v  = ldsf[MV_F + (p * 8 + G) * TK + (HG)];                 \
                int   id = __float_as_int(ldsf[MI_F + (p * 8 + G) * TK + (HG)]); \
                if (v > bv || (v == bv && id < bi)) { bv = v; bi = id; bg = G; } \
            }
            SEL(0, h0) SEL(1, h1) SEL(2, h2) SEL(3, h3)
            SEL(4, h4) SEL(5, h5) SEL(6, h6) SEL(7, h7)
#undef SEL
            ov[o] = bv; oi[o] = bi;
            h0 += (bg == 0); h1 += (bg == 1); h2 += (bg == 2); h3 += (bg == 3);
            h4 += (bg == 4); h5 += (bg == 5); h6 += (bg == 6); h7 += (bg == 7);
        }
        float pv[TK];
#pragma unroll
        for (int o = 0; o < TK; ++o) pv[o] = __expf(ov[o] - mstar) / Z;
        float pmax = pv[0];
        float wgt[TK]; float W = 0.0f;
#pragma unroll
        for (int o = 0; o < TK; ++o) { wgt[o] = __expf(pv[o] - pmax); W += wgt[o]; }
#pragma unroll
        for (int o = 0; o < TK; ++o) {
            ldsf[WB_F + p * TK + o] = wgt[o] / W;
            ldsf[IB_F + p * TK + o] = __int_as_float(oi[o]);
        }
    }
    __syncthreads();

    // ---- epilogue: out[:, c, n] = sum_k w_k * mempool[idx_k][c] ----
    {
        const int ep = t & 63, cg = t >> 6;   // 8 c-groups x 64 channels
        float wr[TK]; const float* rows[TK];
#pragma unroll
        for (int o = 0; o < TK; ++o) {
            wr[o]   = ldsf[WB_F + ep * TK + o];
            rows[o] = mp + (size_t)__float_as_int(ldsf[IB_F + ep * TK + o]) * DIMC;
        }
        float* obase = ob + n0 + ep;
#pragma unroll 4
        for (int cc = 0; cc < 16; ++cc) {
            int c = cg * 64 + cc * 4;
            f4 a = {0.0f, 0.0f, 0.0f, 0.0f};
#pragma unroll
            for (int o = 0; o < TK; ++o) {
                f4 rv = *(const f4*)(rows[o] + c);
#pragma unroll
                for (int z = 0; z < 4; ++z) a[z] = fmaf(wr[o], rv[z], a[z]);
            }
#pragma unroll
            for (int z = 0; z < 4; ++z) obase[(size_t)(c + z) * 1024] = a[z];
        }
    }
}

extern "C" void kernel_launch(void* const* d_in, const int* in_sizes, int n_in,
                              void* d_out, int out_size, void* d_ws, size_t ws_size,
                              hipStream_t stream) {
    const float* x0  = (const float*)d_in[0];
    const float* x1  = (const float*)d_in[1];
    const float* mpl = (const float*)d_in[2];
    float* out = (float*)d_out;
    u16* ws = (u16*)d_ws;

    preconv_kernel<<<dim3(1024), dim3(256), 0, stream>>>(mpl, ws);
    memorize_mfma<<<dim3(512), dim3(TPB), LDS_BYTES, stream>>>(x0, x1, mpl, ws, out);
}